// Round 1
// baseline (288.758 us; speedup 1.0000x reference)
//
#include <hip/hip_runtime.h>
#include <math.h>

#define BB 256
#define SS 128
#define DD 768
#define MASK_ID 103

__constant__ int c_ids[21] = {
    2307, 2204, 3835, 2157, 6581, 2986, 5151, 3893,   // g0 (8)
    7929, 24791, 8699, 4257, 16021, 6623,             // g1 (6)
    6659, 2919, 11771, 3532, 11325, 4997, 13135       // g2 (7)
};

__device__ __forceinline__ float waveReduceSum(float v) {
    #pragma unroll
    for (int off = 32; off > 0; off >>= 1) v += __shfl_down(v, off, 64);
    return v;
}

__device__ __forceinline__ float waveReduceMax(float v) {
    #pragma unroll
    for (int off = 32; off > 0; off >>= 1) v = fmaxf(v, __shfl_down(v, off, 64));
    return v;
}

// Kernel 1: per-batch. mask_pos, category_out, scores (valid only), softmax,
// att; writes feats = [att, mask_logits] (B x 1536) to ws, cat_out to d_out.
__global__ __launch_bounds__(256) void k_att(
    const float* __restrict__ bert, const int* __restrict__ ids,
    const int* __restrict__ len, const float* __restrict__ senti_w,
    const float* __restrict__ senti_b, float* __restrict__ cat_out,
    float* __restrict__ feats)
{
    __shared__ float s_mask[DD];
    __shared__ float s_sc[SS];
    __shared__ float s_red[8];
    __shared__ int s_mp;

    const int b = blockIdx.x;
    const int tid = threadIdx.x;
    const int lane = tid & 63;
    const int wave = tid >> 6;

    if (tid == 0) s_mp = SS;
    __syncthreads();
    if (tid < SS && ids[b * SS + tid] == MASK_ID) atomicMin(&s_mp, tid);
    __syncthreads();
    const int mp = (s_mp == SS) ? 0 : s_mp;   // argmax of all-False -> 0
    const int L = len[b];

    const float* base = bert + (size_t)b * SS * DD;
    const float* mrow = base + (size_t)mp * DD;

    // load mask row to LDS; category partial dots on pooler (row 0)
    float c0 = 0.f, c1 = 0.f;
    for (int d = tid; d < DD; d += 256) {
        float m = mrow[d];
        s_mask[d] = m;
        float x = base[d];
        c0 += x * senti_w[d];
        c1 += x * senti_w[DD + d];
    }
    c0 = waveReduceSum(c0);
    c1 = waveReduceSum(c1);
    if (lane == 0) { s_red[wave] = c0; s_red[4 + wave] = c1; }
    __syncthreads();
    if (tid == 0) {
        cat_out[b * 2 + 0] = s_red[0] + s_red[1] + s_red[2] + s_red[3] + senti_b[0];
        cat_out[b * 2 + 1] = s_red[4] + s_red[5] + s_red[6] + s_red[7] + senti_b[1];
    }

    // scores_raw for valid s only: each wave takes s = 3+wave, +4, ...
    for (int s = 3 + wave; s < 3 + L; s += 4) {
        const float* row = base + (size_t)s * DD;
        float acc = 0.f;
        #pragma unroll
        for (int i = 0; i < DD / 64; ++i)
            acc += row[lane + 64 * i] * s_mask[lane + 64 * i];
        acc = waveReduceSum(acc);
        if (lane == 0) s_sc[s] = acc;
    }
    __syncthreads();

    // softmax over [3, 3+L)
    const bool valid = (tid >= 3 && tid < 3 + L);
    float v = valid ? s_sc[tid] : -INFINITY;
    float m = waveReduceMax(v);
    __syncthreads();                    // s_red reuse (cat partials consumed)
    if (lane == 0) s_red[wave] = m;
    __syncthreads();
    const float bm = fmaxf(fmaxf(s_red[0], s_red[1]), fmaxf(s_red[2], s_red[3]));
    float e = valid ? expf(v - bm) : 0.f;
    float ssum = waveReduceSum(e);
    __syncthreads();
    if (lane == 0) s_red[wave] = ssum;
    __syncthreads();
    const float tot = s_red[0] + s_red[1] + s_red[2] + s_red[3];
    if (tid < SS) s_sc[tid] = e / tot;
    __syncthreads();

    // att[d] = sum_s p[s] * bert[b,s,d]; thread owns d = tid, tid+256, tid+512
    float a0 = 0.f, a1 = 0.f, a2 = 0.f;
    for (int s = 3; s < 3 + L; ++s) {
        const float w = s_sc[s];
        const float* row = base + (size_t)s * DD;
        a0 += w * row[tid];
        a1 += w * row[tid + 256];
        a2 += w * row[tid + 512];
    }
    float* fb = feats + (size_t)b * (2 * DD);
    fb[tid]        = a0;
    fb[tid + 256]  = a1;
    fb[tid + 512]  = a2;
    fb[DD + tid]       = s_mask[tid];
    fb[DD + tid + 256] = s_mask[tid + 256];
    fb[DD + tid + 512] = s_mask[tid + 512];
}

// Kernel 2: h[b][j] = tanh(sum_k feats[b][k]*dense_w[j][k] + dense_b[j])
// 32x32 output tile per block, K-chunks of 32 staged in LDS.
__global__ __launch_bounds__(256) void k_dense(
    const float* __restrict__ feats, const float* __restrict__ dw,
    const float* __restrict__ db, float* __restrict__ h)
{
    __shared__ float As[32][33];
    __shared__ float Bs[32][33];
    const int jt = blockIdx.x;   // 0..23
    const int bt = blockIdx.y;   // 0..7
    const int tid = threadIdx.x;
    const int tx = tid & 15, ty = tid >> 4;
    const int b0 = bt * 32, j0 = jt * 32;
    float acc00 = 0.f, acc01 = 0.f, acc10 = 0.f, acc11 = 0.f;

    for (int k0 = 0; k0 < 2 * DD; k0 += 32) {
        #pragma unroll
        for (int i = 0; i < 4; ++i) {
            int e = tid + i * 256;
            int r = e >> 5, kk = e & 31;
            As[r][kk] = feats[(size_t)(b0 + r) * (2 * DD) + k0 + kk];
            Bs[r][kk] = dw[(size_t)(j0 + r) * (2 * DD) + k0 + kk];
        }
        __syncthreads();
        #pragma unroll
        for (int kk = 0; kk < 32; ++kk) {
            float a0 = As[2 * ty][kk],     a1 = As[2 * ty + 1][kk];
            float w0 = Bs[2 * tx][kk],     w1 = Bs[2 * tx + 1][kk];
            acc00 += a0 * w0; acc01 += a0 * w1;
            acc10 += a1 * w0; acc11 += a1 * w1;
        }
        __syncthreads();
    }
    const int bb = b0 + 2 * ty, jj = j0 + 2 * tx;
    h[(size_t)bb * DD + jj]           = tanhf(acc00 + db[jj]);
    h[(size_t)bb * DD + jj + 1]       = tanhf(acc01 + db[jj + 1]);
    h[(size_t)(bb + 1) * DD + jj]     = tanhf(acc10 + db[jj]);
    h[(size_t)(bb + 1) * DD + jj + 1] = tanhf(acc11 + db[jj + 1]);
}

// Kernel 3: 21 decoder rows + tanh + tiny (2 x {8,6,7}) matmuls.
__global__ __launch_bounds__(256) void k_dec(
    const float* __restrict__ h, const float* __restrict__ dec_w,
    const float* __restrict__ dec_b, const float* __restrict__ w0,
    const float* __restrict__ w1, const float* __restrict__ w2,
    float* __restrict__ out)   // out = d_out + B*2, layout [b][c][g]
{
    __shared__ float s_h[DD];
    __shared__ float s_p[21];
    const int b = blockIdx.x;
    const int tid = threadIdx.x;
    const int lane = tid & 63, wave = tid >> 6;

    for (int d = tid; d < DD; d += 256) s_h[d] = h[(size_t)b * DD + d];
    __syncthreads();

    for (int idx = wave; idx < 21; idx += 4) {
        const int vid = c_ids[idx];
        const float* wr = dec_w + (size_t)vid * DD;
        float acc = 0.f;
        #pragma unroll
        for (int i = 0; i < DD / 64; ++i)
            acc += s_h[lane + 64 * i] * wr[lane + 64 * i];
        acc = waveReduceSum(acc);
        if (lane == 0) s_p[idx] = tanhf(acc + dec_b[vid]);
    }
    __syncthreads();

    if (tid < 6) {
        const int c = tid / 3, g = tid % 3;
        const float* wg = (g == 0) ? w0 : (g == 1) ? w1 : w2;
        const int n    = (g == 0) ? 8  : (g == 1) ? 6  : 7;
        const int base = (g == 0) ? 0  : (g == 1) ? 8  : 14;
        float acc = 0.f;
        for (int i = 0; i < n; ++i) acc += s_p[base + i] * wg[c * n + i];
        out[(size_t)b * 6 + c * 3 + g] = acc;
    }
}

extern "C" void kernel_launch(void* const* d_in, const int* in_sizes, int n_in,
                              void* d_out, int out_size, void* d_ws, size_t ws_size,
                              hipStream_t stream) {
    const float* bert    = (const float*)d_in[0];
    const int*   ids     = (const int*)  d_in[1];
    const int*   len     = (const int*)  d_in[2];
    const float* senti_w = (const float*)d_in[3];
    const float* senti_b = (const float*)d_in[4];
    const float* dense_w = (const float*)d_in[5];
    const float* dense_b = (const float*)d_in[6];
    const float* dec_w   = (const float*)d_in[7];
    const float* dec_b   = (const float*)d_in[8];
    const float* w0      = (const float*)d_in[9];
    const float* w1      = (const float*)d_in[10];
    const float* w2      = (const float*)d_in[11];
    float* out = (float*)d_out;

    float* feats = (float*)d_ws;                       // B x 1536
    float* h     = feats + (size_t)BB * 2 * DD;        // B x 768

    k_att<<<BB, 256, 0, stream>>>(bert, ids, len, senti_w, senti_b, out, feats);
    k_dense<<<dim3(24, 8), 256, 0, stream>>>(feats, dense_w, dense_b, h);
    k_dec<<<BB, 256, 0, stream>>>(h, dec_w, dec_b, w0, w1, w2, out + BB * 2);
}

// Round 2
// 230.383 us; speedup vs baseline: 1.2534x; 1.2534x over previous
//
#include <hip/hip_runtime.h>
#include <hip/hip_bf16.h>
#include <math.h>

#define BB 256
#define SS 128
#define DD 768
#define K2 1536
#define MASK_ID 103

typedef __attribute__((ext_vector_type(8))) short short8;
typedef __attribute__((ext_vector_type(4))) float floatx4;

__constant__ int c_ids[21] = {
    2307, 2204, 3835, 2157, 6581, 2986, 5151, 3893,   // g0 (8)
    7929, 24791, 8699, 4257, 16021, 6623,             // g1 (6)
    6659, 2919, 11771, 3532, 11325, 4997, 13135       // g2 (7)
};

__device__ __forceinline__ float waveReduceSum(float v) {
    #pragma unroll
    for (int off = 32; off > 0; off >>= 1) v += __shfl_down(v, off, 64);
    return v;
}
__device__ __forceinline__ float waveReduceMax(float v) {
    #pragma unroll
    for (int off = 32; off > 0; off >>= 1) v = fmaxf(v, __shfl_down(v, off, 64));
    return v;
}
__device__ __forceinline__ unsigned short f2bf(float f) {   // RNE
    unsigned int u = __float_as_uint(f);
    u += 0x7FFF + ((u >> 16) & 1);
    return (unsigned short)(u >> 16);
}

// fp32 -> bf16 conversion (dense_w), float4 in / ushort4 out
__global__ __launch_bounds__(256) void k_cvt(
    const float* __restrict__ src, unsigned short* __restrict__ dst, int n4)
{
    int i = blockIdx.x * 256 + threadIdx.x;
    if (i < n4) {
        float4 v = ((const float4*)src)[i];
        ushort4 o;
        o.x = f2bf(v.x); o.y = f2bf(v.y); o.z = f2bf(v.z); o.w = f2bf(v.w);
        ((ushort4*)dst)[i] = o;
    }
}

// Kernel 1: per-batch (512 threads = 8 waves). mask_pos, category_out,
// scores+softmax, att; writes feats=[att,mask] as bf16; cat_out to d_out.
__global__ __launch_bounds__(512) void k_att(
    const float* __restrict__ bert, const int* __restrict__ ids,
    const int* __restrict__ len, const float* __restrict__ senti_w,
    const float* __restrict__ senti_b, float* __restrict__ cat_out,
    unsigned short* __restrict__ feats)
{
    __shared__ __align__(16) float s_mask[DD];
    __shared__ __align__(16) float s_part[8][DD];   // per-wave att partials
    __shared__ float s_sc[SS];
    __shared__ float s_red[16];
    __shared__ int s_mp;

    const int b = blockIdx.x;
    const int tid = threadIdx.x;
    const int lane = tid & 63;
    const int wave = tid >> 6;

    if (tid == 0) s_mp = SS;
    __syncthreads();
    if (tid < SS && ids[b * SS + tid] == MASK_ID) atomicMin(&s_mp, tid);
    __syncthreads();
    const int mp = (s_mp == SS) ? 0 : s_mp;
    const int L = len[b];
    const float* base = bert + (size_t)b * SS * DD;
    const float* mrow = base + (size_t)mp * DD;

    // mask row -> LDS; category dot on pooler (row 0)
    float c0 = 0.f, c1 = 0.f;
    for (int d = tid; d < DD; d += 512) {
        s_mask[d] = mrow[d];
        float x = base[d];
        c0 += x * senti_w[d];
        c1 += x * senti_w[DD + d];
    }
    c0 = waveReduceSum(c0);
    c1 = waveReduceSum(c1);
    if (lane == 0) { s_red[wave] = c0; s_red[8 + wave] = c1; }
    __syncthreads();
    if (tid == 0) {
        float t0 = 0.f, t1 = 0.f;
        #pragma unroll
        for (int w = 0; w < 8; ++w) { t0 += s_red[w]; t1 += s_red[8 + w]; }
        cat_out[b * 2 + 0] = t0 + senti_b[0];
        cat_out[b * 2 + 1] = t1 + senti_b[1];
    }

    // scores_raw, valid s only; waves split s 8-way; float4 loads
    const float4* m4 = (const float4*)s_mask;
    for (int s = 3 + wave; s < 3 + L; s += 8) {
        const float4* row = (const float4*)(base + (size_t)s * DD);
        float acc = 0.f;
        #pragma unroll
        for (int i = 0; i < 3; ++i) {
            float4 r = row[lane + 64 * i];
            float4 mm = m4[lane + 64 * i];
            acc += r.x * mm.x + r.y * mm.y + r.z * mm.z + r.w * mm.w;
        }
        acc = waveReduceSum(acc);
        if (lane == 0) s_sc[s] = acc;
    }
    __syncthreads();

    // softmax over [3, 3+L)  (L <= 104, so valid tids are in waves 0-1 only)
    const bool valid = (tid >= 3 && tid < 3 + L);
    float v = valid ? s_sc[tid] : -INFINITY;
    float mx = waveReduceMax(v);
    __syncthreads();
    if (lane == 0) s_red[wave] = mx;
    __syncthreads();
    float bm = s_red[0];
    #pragma unroll
    for (int w = 1; w < 8; ++w) bm = fmaxf(bm, s_red[w]);
    float e = valid ? expf(v - bm) : 0.f;
    float ssum = waveReduceSum(e);
    __syncthreads();
    if (lane == 0) s_red[wave] = ssum;
    __syncthreads();
    float tot = 0.f;
    #pragma unroll
    for (int w = 0; w < 8; ++w) tot += s_red[w];
    if (tid < SS) s_sc[tid] = e / tot;
    __syncthreads();

    // att: waves split s; lane owns d = 4*lane + 256*i + c (float4 each)
    float4 a0 = {0,0,0,0}, a1 = {0,0,0,0}, a2 = {0,0,0,0};
    for (int s = 3 + wave; s < 3 + L; s += 8) {
        const float w = s_sc[s];
        const float4* row = (const float4*)(base + (size_t)s * DD);
        float4 r0 = row[lane], r1 = row[lane + 64], r2 = row[lane + 128];
        a0.x += w * r0.x; a0.y += w * r0.y; a0.z += w * r0.z; a0.w += w * r0.w;
        a1.x += w * r1.x; a1.y += w * r1.y; a1.z += w * r1.z; a1.w += w * r1.w;
        a2.x += w * r2.x; a2.y += w * r2.y; a2.z += w * r2.z; a2.w += w * r2.w;
    }
    float4* pw = (float4*)s_part[wave];
    pw[lane] = a0; pw[lane + 64] = a1; pw[lane + 128] = a2;
    __syncthreads();

    // reduce 8 wave-partials, emit feats = [att, mask] as bf16
    unsigned short* fb = feats + (size_t)b * K2;
    for (int d = tid; d < DD; d += 512) {
        float a = 0.f;
        #pragma unroll
        for (int w = 0; w < 8; ++w) a += s_part[w][d];
        fb[d] = f2bf(a);
        fb[DD + d] = f2bf(s_mask[d]);
    }
}

// Kernel 2 (MFMA): h[b][j] = tanh(feats[b][:] . dw[j][:] + db[j])
// wave computes 16x16 tile via 48x mfma_f32_16x16x32_bf16, frags from global.
__global__ __launch_bounds__(256) void k_dense(
    const unsigned short* __restrict__ featsb,
    const unsigned short* __restrict__ dwb,
    const float* __restrict__ db, float* __restrict__ h)
{
    const int tid = threadIdx.x;
    const int lane = tid & 63, wave = tid >> 6;
    const int b0 = blockIdx.y * 32 + (wave >> 1) * 16;
    const int j0 = blockIdx.x * 32 + (wave & 1) * 16;
    const int m = lane & 15, q = lane >> 4;

    const short8* Arow = (const short8*)(featsb + (size_t)(b0 + m) * K2);
    const short8* Brow = (const short8*)(dwb + (size_t)(j0 + m) * K2);
    floatx4 acc = {0.f, 0.f, 0.f, 0.f};
    #pragma unroll 8
    for (int k8 = 0; k8 < K2 / 8; k8 += 4) {   // 48 iters, K-step 32
        short8 a = Arow[k8 + q];
        short8 w = Brow[k8 + q];
        acc = __builtin_amdgcn_mfma_f32_16x16x32_bf16(a, w, acc, 0, 0, 0);
    }
    const int col = j0 + m;           // C/D: col = lane&15
    const int rb = b0 + q * 4;        //      row = quad*4 + reg
    const float bias = db[col];
    #pragma unroll
    for (int r = 0; r < 4; ++r)
        h[(size_t)(rb + r) * DD + col] = tanhf(acc[r] + bias);
}

// Kernel 3: 21 decoder rows + tanh + tiny (2 x {8,6,7}) matmuls.
__global__ __launch_bounds__(256) void k_dec(
    const float* __restrict__ h, const float* __restrict__ dec_w,
    const float* __restrict__ dec_b, const float* __restrict__ w0,
    const float* __restrict__ w1, const float* __restrict__ w2,
    float* __restrict__ out)   // out = d_out + B*2, layout [b][c][g]
{
    __shared__ __align__(16) float s_h[DD];
    __shared__ float s_p[21];
    const int b = blockIdx.x;
    const int tid = threadIdx.x;
    const int lane = tid & 63, wave = tid >> 6;

    for (int d = tid; d < DD; d += 256) s_h[d] = h[(size_t)b * DD + d];
    __syncthreads();

    for (int idx = wave; idx < 21; idx += 4) {
        const int vid = c_ids[idx];
        const float* wr = dec_w + (size_t)vid * DD;
        float acc = 0.f;
        #pragma unroll
        for (int i = 0; i < DD / 64; ++i)
            acc += s_h[lane + 64 * i] * wr[lane + 64 * i];
        acc = waveReduceSum(acc);
        if (lane == 0) s_p[idx] = tanhf(acc + dec_b[vid]);
    }
    __syncthreads();

    if (tid < 6) {
        const int c = tid / 3, g = tid % 3;
        const float* wg = (g == 0) ? w0 : (g == 1) ? w1 : w2;
        const int n    = (g == 0) ? 8  : (g == 1) ? 6  : 7;
        const int base = (g == 0) ? 0  : (g == 1) ? 8  : 14;
        float acc = 0.f;
        for (int i = 0; i < n; ++i) acc += s_p[base + i] * wg[c * n + i];
        out[(size_t)b * 6 + c * 3 + g] = acc;
    }
}

extern "C" void kernel_launch(void* const* d_in, const int* in_sizes, int n_in,
                              void* d_out, int out_size, void* d_ws, size_t ws_size,
                              hipStream_t stream) {
    const float* bert    = (const float*)d_in[0];
    const int*   ids     = (const int*)  d_in[1];
    const int*   len     = (const int*)  d_in[2];
    const float* senti_w = (const float*)d_in[3];
    const float* senti_b = (const float*)d_in[4];
    const float* dense_w = (const float*)d_in[5];
    const float* dense_b = (const float*)d_in[6];
    const float* dec_w   = (const float*)d_in[7];
    const float* dec_b   = (const float*)d_in[8];
    const float* w0      = (const float*)d_in[9];
    const float* w1      = (const float*)d_in[10];
    const float* w2      = (const float*)d_in[11];
    float* out = (float*)d_out;

    // ws layout (16B aligned chunks)
    unsigned short* feats = (unsigned short*)d_ws;            // B x 1536 bf16
    unsigned short* dwb   = feats + (size_t)BB * K2;          // 768x1536 bf16
    float* h = (float*)(dwb + (size_t)DD * K2);               // B x 768 fp32

    const int n4 = DD * K2 / 4;   // 294912
    k_cvt<<<(n4 + 255) / 256, 256, 0, stream>>>(dense_w, dwb, n4);
    k_att<<<BB, 512, 0, stream>>>(bert, ids, len, senti_w, senti_b, out, feats);
    k_dense<<<dim3(24, 8), 256, 0, stream>>>(feats, dwb, dense_b, h);
    k_dec<<<BB, 256, 0, stream>>>(h, dec_w, dec_b, w0, w1, w2, out + BB * 2);
}

// Round 3
// 224.408 us; speedup vs baseline: 1.2868x; 1.0266x over previous
//
#include <hip/hip_runtime.h>
#include <hip/hip_bf16.h>
#include <math.h>

#define BB 256
#define SS 128
#define DD 768
#define K2 1536
#define MASK_ID 103

typedef __attribute__((ext_vector_type(8))) short short8;
typedef __attribute__((ext_vector_type(4))) float floatx4;

__constant__ int c_ids[21] = {
    2307, 2204, 3835, 2157, 6581, 2986, 5151, 3893,   // g0 (8)
    7929, 24791, 8699, 4257, 16021, 6623,             // g1 (6)
    6659, 2919, 11771, 3532, 11325, 4997, 13135       // g2 (7)
};

__device__ __forceinline__ float waveReduceSum(float v) {       // lane0 holds sum
    #pragma unroll
    for (int off = 32; off > 0; off >>= 1) v += __shfl_down(v, off, 64);
    return v;
}
__device__ __forceinline__ float waveReduceSumAll(float v) {    // all lanes hold sum
    #pragma unroll
    for (int off = 32; off > 0; off >>= 1) v += __shfl_xor(v, off, 64);
    return v;
}
__device__ __forceinline__ unsigned short f2bf(float f) {   // RNE
    unsigned int u = __float_as_uint(f);
    u += 0x7FFF + ((u >> 16) & 1);
    return (unsigned short)(u >> 16);
}

// fp32 -> bf16 conversion (dense_w), float4 in / ushort4 out
__global__ __launch_bounds__(256) void k_cvt(
    const float* __restrict__ src, unsigned short* __restrict__ dst, int n4)
{
    int i = blockIdx.x * 256 + threadIdx.x;
    if (i < n4) {
        float4 v = ((const float4*)src)[i];
        ushort4 o;
        o.x = f2bf(v.x); o.y = f2bf(v.y); o.z = f2bf(v.z); o.w = f2bf(v.w);
        ((ushort4*)dst)[i] = o;
    }
}

// Kernel 1: per-batch, 1024 threads = 16 waves. Single pass over valid rows:
// online-softmax (flash-style) — row stays in registers between the score dot
// and the att accumulate, so bert is read ONCE. Emits feats=[att,mask] bf16.
__global__ __launch_bounds__(1024) void k_att(
    const float* __restrict__ bert, const int* __restrict__ ids,
    const int* __restrict__ len, const float* __restrict__ senti_w,
    const float* __restrict__ senti_b, float* __restrict__ cat_out,
    unsigned short* __restrict__ feats)
{
    __shared__ __align__(16) float s_mask[DD];
    __shared__ __align__(16) float s_part[16][DD];   // per-wave att partials
    __shared__ float s_m[16], s_l[16], s_scale[16];
    __shared__ float s_red[32];
    __shared__ float s_M;
    __shared__ int s_mp;

    const int b = blockIdx.x;
    const int tid = threadIdx.x;
    const int lane = tid & 63;
    const int wave = tid >> 6;     // 0..15

    if (tid == 0) s_mp = SS;
    __syncthreads();
    if (tid < SS && ids[b * SS + tid] == MASK_ID) atomicMin(&s_mp, tid);
    __syncthreads();
    const int mp = (s_mp == SS) ? 0 : s_mp;   // argmax of all-False -> 0
    const int L = len[b];
    const float* base = bert + (size_t)b * SS * DD;
    const float* mrow = base + (size_t)mp * DD;

    // mask row -> LDS; category dot on pooler (row 0)
    float c0 = 0.f, c1 = 0.f;
    if (tid < DD) {
        s_mask[tid] = mrow[tid];
        float x = base[tid];
        c0 = x * senti_w[tid];
        c1 = x * senti_w[DD + tid];
    }
    c0 = waveReduceSum(c0);
    c1 = waveReduceSum(c1);
    if (lane == 0) { s_red[wave] = c0; s_red[16 + wave] = c1; }
    __syncthreads();
    if (tid == 0) {
        float t0 = 0.f, t1 = 0.f;
        #pragma unroll
        for (int w = 0; w < 16; ++w) { t0 += s_red[w]; t1 += s_red[16 + w]; }
        cat_out[b * 2 + 0] = t0 + senti_b[0];
        cat_out[b * 2 + 1] = t1 + senti_b[1];
    }

    // single pass: score + online softmax + att accumulate, rows split 16-way
    const float4* m4 = (const float4*)s_mask;
    float4 mm0 = m4[lane], mm1 = m4[lane + 64], mm2 = m4[lane + 128];
    float4 A0 = {0,0,0,0}, A1 = {0,0,0,0}, A2 = {0,0,0,0};
    float mloc = -INFINITY, lloc = 0.f;
    for (int s = 3 + wave; s < 3 + L; s += 16) {
        const float4* row = (const float4*)(base + (size_t)s * DD);
        float4 r0 = row[lane], r1 = row[lane + 64], r2 = row[lane + 128];
        float d = r0.x * mm0.x + r0.y * mm0.y + r0.z * mm0.z + r0.w * mm0.w
                + r1.x * mm1.x + r1.y * mm1.y + r1.z * mm1.z + r1.w * mm1.w
                + r2.x * mm2.x + r2.y * mm2.y + r2.z * mm2.z + r2.w * mm2.w;
        d = waveReduceSumAll(d);
        float mnew = fmaxf(mloc, d);
        float scale = __expf(mloc - mnew);   // first iter: exp(-inf)=0
        float p = __expf(d - mnew);
        lloc = lloc * scale + p;
        A0.x = A0.x * scale + p * r0.x; A0.y = A0.y * scale + p * r0.y;
        A0.z = A0.z * scale + p * r0.z; A0.w = A0.w * scale + p * r0.w;
        A1.x = A1.x * scale + p * r1.x; A1.y = A1.y * scale + p * r1.y;
        A1.z = A1.z * scale + p * r1.z; A1.w = A1.w * scale + p * r1.w;
        A2.x = A2.x * scale + p * r2.x; A2.y = A2.y * scale + p * r2.y;
        A2.z = A2.z * scale + p * r2.z; A2.w = A2.w * scale + p * r2.w;
        mloc = mnew;
    }
    if (lane == 0) { s_m[wave] = mloc; s_l[wave] = lloc; }
    float4* pw = (float4*)s_part[wave];
    pw[lane] = A0; pw[lane + 64] = A1; pw[lane + 128] = A2;
    __syncthreads();

    // combine 16 wave-partials
    if (tid == 0) {
        float M = -INFINITY;
        #pragma unroll
        for (int w = 0; w < 16; ++w) M = fmaxf(M, s_m[w]);
        s_M = M;
    }
    __syncthreads();
    if (tid < 16) s_scale[tid] = __expf(s_m[tid] - s_M);  // empty wave -> 0
    __syncthreads();

    if (tid < DD) {
        float lt = 0.f, a = 0.f;
        #pragma unroll
        for (int w = 0; w < 16; ++w) {
            lt += s_scale[w] * s_l[w];
            a  += s_scale[w] * s_part[w][tid];
        }
        unsigned short* fb = feats + (size_t)b * K2;
        fb[tid]      = f2bf(a / lt);
        fb[DD + tid] = f2bf(s_mask[tid]);
    }
}

// Kernel 2 (MFMA): h[b][j] = tanh(feats[b][:] . dw[j][:] + db[j])
// wave computes 16x16 tile via 48x mfma_f32_16x16x32_bf16, frags from global.
__global__ __launch_bounds__(256) void k_dense(
    const unsigned short* __restrict__ featsb,
    const unsigned short* __restrict__ dwb,
    const float* __restrict__ db, float* __restrict__ h)
{
    const int tid = threadIdx.x;
    const int lane = tid & 63, wave = tid >> 6;
    const int b0 = blockIdx.y * 32 + (wave >> 1) * 16;
    const int j0 = blockIdx.x * 32 + (wave & 1) * 16;
    const int m = lane & 15, q = lane >> 4;

    const short8* Arow = (const short8*)(featsb + (size_t)(b0 + m) * K2);
    const short8* Brow = (const short8*)(dwb + (size_t)(j0 + m) * K2);
    floatx4 acc = {0.f, 0.f, 0.f, 0.f};
    #pragma unroll 8
    for (int k8 = 0; k8 < K2 / 8; k8 += 4) {   // 48 iters, K-step 32
        short8 a = Arow[k8 + q];
        short8 w = Brow[k8 + q];
        acc = __builtin_amdgcn_mfma_f32_16x16x32_bf16(a, w, acc, 0, 0, 0);
    }
    const int col = j0 + m;           // C/D: col = lane&15
    const int rb = b0 + q * 4;        //      row = quad*4 + reg
    const float bias = db[col];
    #pragma unroll
    for (int r = 0; r < 4; ++r)
        h[(size_t)(rb + r) * DD + col] = tanhf(acc[r] + bias);
}

// Kernel 3: 21 decoder rows + tanh + tiny (2 x {8,6,7}) matmuls.
__global__ __launch_bounds__(256) void k_dec(
    const float* __restrict__ h, const float* __restrict__ dec_w,
    const float* __restrict__ dec_b, const float* __restrict__ w0,
    const float* __restrict__ w1, const float* __restrict__ w2,
    float* __restrict__ out)   // out = d_out + B*2, layout [b][c][g]
{
    __shared__ __align__(16) float s_h[DD];
    __shared__ float s_p[21];
    const int b = blockIdx.x;
    const int tid = threadIdx.x;
    const int lane = tid & 63, wave = tid >> 6;

    for (int d = tid; d < DD; d += 256) s_h[d] = h[(size_t)b * DD + d];
    __syncthreads();

    for (int idx = wave; idx < 21; idx += 4) {
        const int vid = c_ids[idx];
        const float* wr = dec_w + (size_t)vid * DD;
        float acc = 0.f;
        #pragma unroll
        for (int i = 0; i < DD / 64; ++i)
            acc += s_h[lane + 64 * i] * wr[lane + 64 * i];
        acc = waveReduceSum(acc);
        if (lane == 0) s_p[idx] = tanhf(acc + dec_b[vid]);
    }
    __syncthreads();

    if (tid < 6) {
        const int c = tid / 3, g = tid % 3;
        const float* wg = (g == 0) ? w0 : (g == 1) ? w1 : w2;
        const int n    = (g == 0) ? 8  : (g == 1) ? 6  : 7;
        const int base = (g == 0) ? 0  : (g == 1) ? 8  : 14;
        float acc = 0.f;
        for (int i = 0; i < n; ++i) acc += s_p[base + i] * wg[c * n + i];
        out[(size_t)b * 6 + c * 3 + g] = acc;
    }
}

extern "C" void kernel_launch(void* const* d_in, const int* in_sizes, int n_in,
                              void* d_out, int out_size, void* d_ws, size_t ws_size,
                              hipStream_t stream) {
    const float* bert    = (const float*)d_in[0];
    const int*   ids     = (const int*)  d_in[1];
    const int*   len     = (const int*)  d_in[2];
    const float* senti_w = (const float*)d_in[3];
    const float* senti_b = (const float*)d_in[4];
    const float* dense_w = (const float*)d_in[5];
    const float* dense_b = (const float*)d_in[6];
    const float* dec_w   = (const float*)d_in[7];
    const float* dec_b   = (const float*)d_in[8];
    const float* w0      = (const float*)d_in[9];
    const float* w1      = (const float*)d_in[10];
    const float* w2      = (const float*)d_in[11];
    float* out = (float*)d_out;

    // ws layout (16B aligned chunks)
    unsigned short* feats = (unsigned short*)d_ws;            // B x 1536 bf16
    unsigned short* dwb   = feats + (size_t)BB * K2;          // 768x1536 bf16
    float* h = (float*)(dwb + (size_t)DD * K2);               // B x 768 fp32

    const int n4 = DD * K2 / 4;   // 294912
    k_cvt<<<(n4 + 255) / 256, 256, 0, stream>>>(dense_w, dwb, n4);
    k_att<<<BB, 1024, 0, stream>>>(bert, ids, len, senti_w, senti_b, out, feats);
    k_dense<<<dim3(24, 8), 256, 0, stream>>>(feats, dwb, dense_b, h);
    k_dec<<<BB, 256, 0, stream>>>(h, dec_w, dec_b, w0, w1, w2, out + BB * 2);
}

// Round 4
// 222.379 us; speedup vs baseline: 1.2985x; 1.0091x over previous
//
#include <hip/hip_runtime.h>
#include <hip/hip_bf16.h>
#include <math.h>

#define BB 256
#define SS 128
#define DD 768
#define K2 1536
#define MASK_ID 103

typedef __attribute__((ext_vector_type(8))) short short8;
typedef __attribute__((ext_vector_type(4))) float floatx4;

__constant__ int c_ids[21] = {
    2307, 2204, 3835, 2157, 6581, 2986, 5151, 3893,   // g0 (8)
    7929, 24791, 8699, 4257, 16021, 6623,             // g1 (6)
    6659, 2919, 11771, 3532, 11325, 4997, 13135       // g2 (7)
};

__device__ __forceinline__ float waveReduceSum(float v) {       // lane0 holds sum
    #pragma unroll
    for (int off = 32; off > 0; off >>= 1) v += __shfl_down(v, off, 64);
    return v;
}
__device__ __forceinline__ float waveReduceSumAll(float v) {    // all lanes hold sum
    #pragma unroll
    for (int off = 32; off > 0; off >>= 1) v += __shfl_xor(v, off, 64);
    return v;
}
__device__ __forceinline__ unsigned short f2bf(float f) {   // RNE
    unsigned int u = __float_as_uint(f);
    u += 0x7FFF + ((u >> 16) & 1);
    return (unsigned short)(u >> 16);
}

// Kernel 1: per-batch, 1024 threads = 16 waves.
//  - prologue: grid-stride fp32->bf16 convert of dense_w (replaces k_cvt;
//    VMEM hides under this kernel's latency stalls)
//  - single pass over valid rows with online softmax; 2-row ILP per wave.
// Emits feats=[att,mask] bf16; cat_out to d_out.
__global__ __launch_bounds__(1024) void k_att(
    const float* __restrict__ bert, const int* __restrict__ ids,
    const int* __restrict__ len, const float* __restrict__ senti_w,
    const float* __restrict__ senti_b, float* __restrict__ cat_out,
    unsigned short* __restrict__ feats,
    const float* __restrict__ dense_w, unsigned short* __restrict__ dwb)
{
    __shared__ __align__(16) float s_mask[DD];
    __shared__ __align__(16) float s_part[16][DD];   // per-wave att partials
    __shared__ float s_m[16], s_l[16], s_scale[16];
    __shared__ float s_red[32];
    __shared__ float s_M;
    __shared__ int s_mp;

    const int b = blockIdx.x;
    const int tid = threadIdx.x;
    const int lane = tid & 63;
    const int wave = tid >> 6;     // 0..15

    if (tid == 0) s_mp = SS;

    // fused dense_w fp32 -> bf16 (n4 = 294912 float4s over 262144 threads)
    {
        const int n4 = DD * K2 / 4;
        for (int i = b * 1024 + tid; i < n4; i += BB * 1024) {
            float4 v = ((const float4*)dense_w)[i];
            ushort4 o;
            o.x = f2bf(v.x); o.y = f2bf(v.y); o.z = f2bf(v.z); o.w = f2bf(v.w);
            ((ushort4*)dwb)[i] = o;
        }
    }

    __syncthreads();
    if (tid < SS && ids[b * SS + tid] == MASK_ID) atomicMin(&s_mp, tid);
    __syncthreads();
    const int mp = (s_mp == SS) ? 0 : s_mp;   // argmax of all-False -> 0
    const int L = len[b];
    const float* base = bert + (size_t)b * SS * DD;
    const float* mrow = base + (size_t)mp * DD;

    // mask row -> LDS; category dot on pooler (row 0)
    float c0 = 0.f, c1 = 0.f;
    if (tid < DD) {
        s_mask[tid] = mrow[tid];
        float x = base[tid];
        c0 = x * senti_w[tid];
        c1 = x * senti_w[DD + tid];
    }
    c0 = waveReduceSum(c0);
    c1 = waveReduceSum(c1);
    if (lane == 0) { s_red[wave] = c0; s_red[16 + wave] = c1; }
    __syncthreads();
    if (tid == 0) {
        float t0 = 0.f, t1 = 0.f;
        #pragma unroll
        for (int w = 0; w < 16; ++w) { t0 += s_red[w]; t1 += s_red[16 + w]; }
        cat_out[b * 2 + 0] = t0 + senti_b[0];
        cat_out[b * 2 + 1] = t1 + senti_b[1];
    }

    // single pass: score + online softmax + att accumulate; rows split 16-way,
    // 2 rows in flight per iteration for load-latency overlap.
    const float4* m4 = (const float4*)s_mask;
    float4 mm0 = m4[lane], mm1 = m4[lane + 64], mm2 = m4[lane + 128];
    float4 A0 = {0,0,0,0}, A1 = {0,0,0,0}, A2 = {0,0,0,0};
    float mloc = -INFINITY, lloc = 0.f;
    int s = 3 + wave;
    for (; s + 16 < 3 + L; s += 32) {
        const float4* ra = (const float4*)(base + (size_t)s * DD);
        const float4* rb = (const float4*)(base + (size_t)(s + 16) * DD);
        float4 a0 = ra[lane], a1 = ra[lane + 64], a2 = ra[lane + 128];
        float4 b0 = rb[lane], b1 = rb[lane + 64], b2 = rb[lane + 128];
        float d1 = a0.x*mm0.x + a0.y*mm0.y + a0.z*mm0.z + a0.w*mm0.w
                 + a1.x*mm1.x + a1.y*mm1.y + a1.z*mm1.z + a1.w*mm1.w
                 + a2.x*mm2.x + a2.y*mm2.y + a2.z*mm2.z + a2.w*mm2.w;
        float d2 = b0.x*mm0.x + b0.y*mm0.y + b0.z*mm0.z + b0.w*mm0.w
                 + b1.x*mm1.x + b1.y*mm1.y + b1.z*mm1.z + b1.w*mm1.w
                 + b2.x*mm2.x + b2.y*mm2.y + b2.z*mm2.z + b2.w*mm2.w;
        d1 = waveReduceSumAll(d1);
        d2 = waveReduceSumAll(d2);
        float mnew = fmaxf(mloc, fmaxf(d1, d2));
        float scale = __expf(mloc - mnew);   // first iter: exp(-inf)=0
        float p1 = __expf(d1 - mnew);
        float p2 = __expf(d2 - mnew);
        lloc = lloc * scale + p1 + p2;
        A0.x = A0.x*scale + p1*a0.x + p2*b0.x; A0.y = A0.y*scale + p1*a0.y + p2*b0.y;
        A0.z = A0.z*scale + p1*a0.z + p2*b0.z; A0.w = A0.w*scale + p1*a0.w + p2*b0.w;
        A1.x = A1.x*scale + p1*a1.x + p2*b1.x; A1.y = A1.y*scale + p1*a1.y + p2*b1.y;
        A1.z = A1.z*scale + p1*a1.z + p2*b1.z; A1.w = A1.w*scale + p1*a1.w + p2*b1.w;
        A2.x = A2.x*scale + p1*a2.x + p2*b2.x; A2.y = A2.y*scale + p1*a2.y + p2*b2.y;
        A2.z = A2.z*scale + p1*a2.z + p2*b2.z; A2.w = A2.w*scale + p1*a2.w + p2*b2.w;
        mloc = mnew;
    }
    for (; s < 3 + L; s += 16) {
        const float4* ra = (const float4*)(base + (size_t)s * DD);
        float4 a0 = ra[lane], a1 = ra[lane + 64], a2 = ra[lane + 128];
        float d1 = a0.x*mm0.x + a0.y*mm0.y + a0.z*mm0.z + a0.w*mm0.w
                 + a1.x*mm1.x + a1.y*mm1.y + a1.z*mm1.z + a1.w*mm1.w
                 + a2.x*mm2.x + a2.y*mm2.y + a2.z*mm2.z + a2.w*mm2.w;
        d1 = waveReduceSumAll(d1);
        float mnew = fmaxf(mloc, d1);
        float scale = __expf(mloc - mnew);
        float p1 = __expf(d1 - mnew);
        lloc = lloc * scale + p1;
        A0.x = A0.x*scale + p1*a0.x; A0.y = A0.y*scale + p1*a0.y;
        A0.z = A0.z*scale + p1*a0.z; A0.w = A0.w*scale + p1*a0.w;
        A1.x = A1.x*scale + p1*a1.x; A1.y = A1.y*scale + p1*a1.y;
        A1.z = A1.z*scale + p1*a1.z; A1.w = A1.w*scale + p1*a1.w;
        A2.x = A2.x*scale + p1*a2.x; A2.y = A2.y*scale + p1*a2.y;
        A2.z = A2.z*scale + p1*a2.z; A2.w = A2.w*scale + p1*a2.w;
        mloc = mnew;
    }
    if (lane == 0) { s_m[wave] = mloc; s_l[wave] = lloc; }
    float4* pw = (float4*)s_part[wave];
    pw[lane] = A0; pw[lane + 64] = A1; pw[lane + 128] = A2;
    __syncthreads();

    // combine 16 wave-partials
    if (tid == 0) {
        float M = -INFINITY;
        #pragma unroll
        for (int w = 0; w < 16; ++w) M = fmaxf(M, s_m[w]);
        s_M = M;
    }
    __syncthreads();
    if (tid < 16) s_scale[tid] = __expf(s_m[tid] - s_M);  // empty wave -> 0
    __syncthreads();

    if (tid < DD) {
        float lt = 0.f, a = 0.f;
        #pragma unroll
        for (int w = 0; w < 16; ++w) {
            lt += s_scale[w] * s_l[w];
            a  += s_scale[w] * s_part[w][tid];
        }
        unsigned short* fb = feats + (size_t)b * K2;
        fb[tid]      = f2bf(a / lt);
        fb[DD + tid] = f2bf(s_mask[tid]);
    }
}

// Kernel 2 (MFMA): h[b][j] = tanh(feats[b][:] . dw[j][:] + db[j])
// 512 thr: wave-quads cover 32x32 tile, wave-pairs split K (24 MFMAs each,
// half the serial chain), LDS combine.
__global__ __launch_bounds__(512) void k_dense(
    const unsigned short* __restrict__ featsb,
    const unsigned short* __restrict__ dwb,
    const float* __restrict__ db, float* __restrict__ h)
{
    __shared__ floatx4 s_acc[4][64];
    const int tid = threadIdx.x;
    const int lane = tid & 63, wave = tid >> 6;   // 0..7
    const int wq = wave & 3, kh = wave >> 2;
    const int b0 = blockIdx.y * 32 + (wq >> 1) * 16;
    const int j0 = blockIdx.x * 32 + (wq & 1) * 16;
    const int m = lane & 15, q = lane >> 4;

    const short8* Arow = (const short8*)(featsb + (size_t)(b0 + m) * K2) + kh * 96;
    const short8* Brow = (const short8*)(dwb + (size_t)(j0 + m) * K2) + kh * 96;
    floatx4 acc = {0.f, 0.f, 0.f, 0.f};
    #pragma unroll 6
    for (int k8 = 0; k8 < 96; k8 += 4) {   // 24 iters, K-step 32
        short8 a = Arow[k8 + q];
        short8 w = Brow[k8 + q];
        acc = __builtin_amdgcn_mfma_f32_16x16x32_bf16(a, w, acc, 0, 0, 0);
    }
    if (kh) s_acc[wq][lane] = acc;
    __syncthreads();
    if (!kh) {
        floatx4 o = s_acc[wq][lane];
        acc.x += o.x; acc.y += o.y; acc.z += o.z; acc.w += o.w;
        const int col = j0 + m;           // C/D: col = lane&15
        const int rb = b0 + q * 4;        //      row = quad*4 + reg
        const float bias = db[col];
        #pragma unroll
        for (int r = 0; r < 4; ++r)
            h[(size_t)(rb + r) * DD + col] = tanhf(acc[r] + bias);
    }
}

// Kernel 3: 21 decoder rows + tanh + tiny (2 x {8,6,7}) matmuls.
__global__ __launch_bounds__(256) void k_dec(
    const float* __restrict__ h, const float* __restrict__ dec_w,
    const float* __restrict__ dec_b, const float* __restrict__ w0,
    const float* __restrict__ w1, const float* __restrict__ w2,
    float* __restrict__ out)   // out = d_out + B*2, layout [b][c][g]
{
    __shared__ __align__(16) float s_h[DD];
    __shared__ float s_p[21];
    const int b = blockIdx.x;
    const int tid = threadIdx.x;
    const int lane = tid & 63, wave = tid >> 6;

    for (int d = tid; d < DD; d += 256) s_h[d] = h[(size_t)b * DD + d];
    __syncthreads();

    for (int idx = wave; idx < 21; idx += 4) {
        const int vid = c_ids[idx];
        const float* wr = dec_w + (size_t)vid * DD;
        float acc = 0.f;
        #pragma unroll
        for (int i = 0; i < DD / 64; ++i)
            acc += s_h[lane + 64 * i] * wr[lane + 64 * i];
        acc = waveReduceSum(acc);
        if (lane == 0) s_p[idx] = tanhf(acc + dec_b[vid]);
    }
    __syncthreads();

    if (tid < 6) {
        const int c = tid / 3, g = tid % 3;
        const float* wg = (g == 0) ? w0 : (g == 1) ? w1 : w2;
        const int n    = (g == 0) ? 8  : (g == 1) ? 6  : 7;
        const int base = (g == 0) ? 0  : (g == 1) ? 8  : 14;
        float acc = 0.f;
        for (int i = 0; i < n; ++i) acc += s_p[base + i] * wg[c * n + i];
        out[(size_t)b * 6 + c * 3 + g] = acc;
    }
}

extern "C" void kernel_launch(void* const* d_in, const int* in_sizes, int n_in,
                              void* d_out, int out_size, void* d_ws, size_t ws_size,
                              hipStream_t stream) {
    const float* bert    = (const float*)d_in[0];
    const int*   ids     = (const int*)  d_in[1];
    const int*   len     = (const int*)  d_in[2];
    const float* senti_w = (const float*)d_in[3];
    const float* senti_b = (const float*)d_in[4];
    const float* dense_w = (const float*)d_in[5];
    const float* dense_b = (const float*)d_in[6];
    const float* dec_w   = (const float*)d_in[7];
    const float* dec_b   = (const float*)d_in[8];
    const float* w0      = (const float*)d_in[9];
    const float* w1      = (const float*)d_in[10];
    const float* w2      = (const float*)d_in[11];
    float* out = (float*)d_out;

    // ws layout (16B aligned chunks)
    unsigned short* feats = (unsigned short*)d_ws;            // B x 1536 bf16
    unsigned short* dwb   = feats + (size_t)BB * K2;          // 768x1536 bf16
    float* h = (float*)(dwb + (size_t)DD * K2);               // B x 768 fp32

    k_att<<<BB, 1024, 0, stream>>>(bert, ids, len, senti_w, senti_b, out,
                                   feats, dense_w, dwb);
    k_dense<<<dim3(24, 8), 512, 0, stream>>>(feats, dwb, dense_b, h);
    k_dec<<<BB, 256, 0, stream>>>(h, dec_w, dec_b, w0, w1, w2, out + BB * 2);
}